// Round 2
// 973.779 us; speedup vs baseline: 1.3248x; 1.3248x over previous
//
#include <hip/hip_runtime.h>
#include <hip/hip_bf16.h>
#include <cstdint>
#include <cstddef>

#define HIDDEN 2048
#define INTER 8192
#define M_TOK 8192   // BATCH * LOCAL_SEQ = 2 * 4096

typedef __attribute__((ext_vector_type(8))) short short8;   // 8 bf16 = 4 VGPRs
typedef __attribute__((ext_vector_type(4))) float float4v;  // MFMA C/D

typedef __hip_bfloat16 bf16;

// ---------------------------------------------------------------------------
// fp32 -> bf16 convert (memory-bound, grid-stride)
// ---------------------------------------------------------------------------
__global__ void cvt_bf16(const float* __restrict__ src, bf16* __restrict__ dst, int n) {
    int idx = blockIdx.x * blockDim.x + threadIdx.x;
    int stride = gridDim.x * blockDim.x;
    for (int i = idx * 4; i < n; i += stride * 4) {
        float4 v = *(const float4*)(src + i);
        union { bf16 h[4]; ushort4 u; } pk;
        pk.h[0] = __float2bfloat16(v.x);
        pk.h[1] = __float2bfloat16(v.y);
        pk.h[2] = __float2bfloat16(v.z);
        pk.h[3] = __float2bfloat16(v.w);
        *(ushort4*)(dst + i) = pk.u;
    }
}

// async global->LDS, 16B per lane; LDS dest = wave-uniform base + lane*16
__device__ __forceinline__ void load16_lds(const bf16* g, bf16* l) {
    __builtin_amdgcn_global_load_lds((const __attribute__((address_space(1))) void*)g,
                                     (__attribute__((address_space(3))) void*)l,
                                     16, 0, 0);
}

// ---------------------------------------------------------------------------
// 256x256-tile, BK=64, 8-wave (512 thr), double-buffered 128 KiB LDS,
// 4 quadrant-phases per K-tile with COUNTED vmcnt (never 0 in main loop),
// setprio(1) around MFMA cluster.
//
// LDS PHYSICAL row order is PERMUTED so each phase's fragment reads touch
// exactly one stage-group for EVERY wave (R1 fix: the previous quadrant
// ledger was wave-dependent -> wm=1 waves raced in-flight A1 stages):
//   A: phys row p = ih*128 + wm*64 + s   <-> global row m0 + wm*128 + ih*64 + s
//   B: phys row p = jh*128 + wn*32 + s   <-> out col  n0 + wn*64 + jh*32 + s
//      (FUSE: phys 0..127 = gate rows n0+p, 128..255 = up rows INTER+n0+p-128)
// Permutation is applied on the GLOBAL source of global_load_lds (LDS dest
// stays linear). Swizzle: row r stores k-chunk c (16 B) at slot c ^ (r&7);
// staged by pre-swizzling the global k-offset per lane.
//
// Phases (snake (ih,jh) = (0,0),(0,1),(1,1),(1,0)), stages for next tile:
//   ph0: read A-grp0(8) B-grp0(4); stage A0'; vmcnt(4)  [retires B1 cur]
//   ph1: read B-grp1(4)          ; stage B0'; vmcnt(4)  [retires A1 cur]
//   ph2: read A-grp1(8)          ; stage B1'; no wait
//   ph3: read B-grp0(4)          ; stage A1'; vmcnt(4)  [retires A0',B0']
// Each wait sits before the phase's first barrier; reads of the covered data
// happen after that phase's SECOND barrier -> {own-wait -> barrier} makes it
// all-wave safe. In-flight never drops below 4 loads (2 stages).
// ---------------------------------------------------------------------------
template<int KDIM, bool FUSE>
__global__ __launch_bounds__(512, 2) void gemm_8ph(const bf16* __restrict__ A,
                                                   const bf16* __restrict__ B,
                                                   bf16* __restrict__ actout,
                                                   float* __restrict__ cout) {
    static_assert(KDIM % 64 == 0, "KDIM multiple of 64");
    __shared__ __align__(16) bf16 sm[2 * 32768];   // 131072 B: 2 buf x (A 16384 + B 16384) elems

    constexpr int NKT = KDIM / 64;

    const int tid  = threadIdx.x;
    const int wave = tid >> 6;
    const int lane = tid & 63;
    const int wm = wave >> 2;          // 0..1 : M-half of C
    const int wn = wave & 3;           // 0..3 : N-quarter of C
    const int lm = lane & 15;
    const int kg = lane >> 4;

    const int m0 = blockIdx.y * 256;
    const int n0 = blockIdx.x * (FUSE ? 128 : 256);

    // ---- staging addresses: issue q writes LDS phys rows q*64 .. q*64+63 ----
    const int srow = wave * 8 + (lane >> 3);           // phys row within issue
    const int scol = ((lane & 7) ^ (lane >> 3)) * 8;   // pre-swizzled global k-chunk
    const bf16* ag[4];
    const bf16* bg[4];
#pragma unroll
    for (int q = 0; q < 4; ++q) {
        // A: issue q = grp*2 + half; phys p = q*64+srow = grp*128 + half*64 + srow
        const int arow = m0 + (q & 1) * 128 + (q >> 1) * 64 + srow;
        ag[q] = A + (size_t)arow * KDIM + scol;
        int brow;
        if (FUSE) {
            // phys p = q*64+srow; p<128 -> gate n0+p ; p>=128 -> up INTER+n0+(p-128)
            brow = n0 + (q >> 1) * (INTER - 128) + q * 64 + srow;
        } else {
            // phys p = q*64+srow; grp=q>>1, t=p&127=wn*32+s -> col n0+wn*64+grp*32+s
            const int t = (q & 1) * 64 + srow;
            brow = n0 + (t >> 5) * 64 + (q >> 1) * 32 + (t & 31);
        }
        bg[q] = B + (size_t)brow * KDIM + scol;
    }
    bf16* const sdA = sm + wave * 512;            // + buf*32768 + q*4096 (+ lane*16B by HW)
    bf16* const sdB = sm + 16384 + wave * 512;

    // ---- fragment read slot offsets (loop-invariant per lane; r&7 == lm&7) ----
    const int sl0 = ((0 * 4 + kg) ^ (lm & 7)) * 8;   // ks = 0
    const int sl1 = ((1 * 4 + kg) ^ (lm & 7)) * 8;   // ks = 1

    float4v acc[8][4];
#pragma unroll
    for (int i = 0; i < 8; i++)
#pragma unroll
        for (int j = 0; j < 4; j++) acc[i][j] = (float4v)0.f;

    short8 af[8];   // current A-half: 4 i-frags x 2 k-steps
    short8 bq[4];   // current B-pair: 2 j-frags x 2 k-steps

#define STAGE_A(h, nb, kn) { \
        load16_lds(ag[(h)*2+0] + (size_t)(kn)*64, sdA + (nb)*32768 + ((h)*2+0)*4096); \
        load16_lds(ag[(h)*2+1] + (size_t)(kn)*64, sdA + (nb)*32768 + ((h)*2+1)*4096); }
#define STAGE_B(h, nb, kn) { \
        load16_lds(bg[(h)*2+0] + (size_t)(kn)*64, sdB + (nb)*32768 + ((h)*2+0)*4096); \
        load16_lds(bg[(h)*2+1] + (size_t)(kn)*64, sdB + (nb)*32768 + ((h)*2+1)*4096); }
#define LOAD_A(ih, smA_) { \
        _Pragma("unroll") \
        for (int i2 = 0; i2 < 4; i2++) { \
            const bf16* p = (smA_) + ((ih) * 128 + wm * 64 + i2 * 16 + lm) * 64; \
            af[i2*2+0] = *(const short8*)(p + sl0); \
            af[i2*2+1] = *(const short8*)(p + sl1); } }
#define LOAD_B(jh, smB_) { \
        _Pragma("unroll") \
        for (int j2 = 0; j2 < 2; j2++) { \
            const bf16* p = (smB_) + ((jh) * 128 + wn * 32 + j2 * 16 + lm) * 64; \
            bq[j2*2+0] = *(const short8*)(p + sl0); \
            bq[j2*2+1] = *(const short8*)(p + sl1); } }
#define MFMA_Q(ih, jh) { \
        _Pragma("unroll") \
        for (int i2 = 0; i2 < 4; i2++) \
        _Pragma("unroll") \
        for (int j2 = 0; j2 < 2; j2++) { \
            acc[(ih)*4+i2][(jh)*2+j2] = __builtin_amdgcn_mfma_f32_16x16x32_bf16(af[i2*2+0], bq[j2*2+0], acc[(ih)*4+i2][(jh)*2+j2], 0, 0, 0); \
            acc[(ih)*4+i2][(jh)*2+j2] = __builtin_amdgcn_mfma_f32_16x16x32_bf16(af[i2*2+1], bq[j2*2+1], acc[(ih)*4+i2][(jh)*2+j2], 0, 0, 0); } }

    // ---- prologue: stage tile 0 into buf 0 in issue order A0,B0,B1,A1 ----
    STAGE_A(0, 0, 0);
    STAGE_B(0, 0, 0);
    STAGE_B(1, 0, 0);
    STAGE_A(1, 0, 0);
    asm volatile("s_waitcnt vmcnt(4)" ::: "memory");   // A0,B0 landed; B1,A1 in flight
    __builtin_amdgcn_s_barrier();

    for (int kt = 0; kt < NKT; ++kt) {
        const int bb = kt & 1;
        const int nb = bb ^ 1;
        const int kn = (kt + 1 < NKT) ? (kt + 1) : 0;   // tail wraps: dead prefetch, never read
        const bf16* smA = sm + bb * 32768;
        const bf16* smB = smA + 16384;

        // ---- phase 0: quadrant (0,0) ----
        LOAD_A(0, smA); LOAD_B(0, smB);
        STAGE_A(0, nb, kn);
        asm volatile("s_waitcnt vmcnt(4)" ::: "memory");   // retires B1(cur) for ph1
        __builtin_amdgcn_s_barrier();
        asm volatile("s_waitcnt lgkmcnt(0)" ::: "memory");
        __builtin_amdgcn_sched_barrier(0);
        __builtin_amdgcn_s_setprio(1);
        MFMA_Q(0, 0);
        __builtin_amdgcn_s_setprio(0);
        __builtin_amdgcn_s_barrier();

        // ---- phase 1: quadrant (0,1) ----
        LOAD_B(1, smB);
        STAGE_B(0, nb, kn);
        asm volatile("s_waitcnt vmcnt(4)" ::: "memory");   // retires A1(cur) for ph2
        __builtin_amdgcn_s_barrier();
        asm volatile("s_waitcnt lgkmcnt(0)" ::: "memory");
        __builtin_amdgcn_sched_barrier(0);
        __builtin_amdgcn_s_setprio(1);
        MFMA_Q(0, 1);
        __builtin_amdgcn_s_setprio(0);
        __builtin_amdgcn_s_barrier();

        // ---- phase 2: quadrant (1,1) ----
        LOAD_A(1, smA);
        STAGE_B(1, nb, kn);
        __builtin_amdgcn_s_barrier();
        asm volatile("s_waitcnt lgkmcnt(0)" ::: "memory");
        __builtin_amdgcn_sched_barrier(0);
        __builtin_amdgcn_s_setprio(1);
        MFMA_Q(1, 1);
        __builtin_amdgcn_s_setprio(0);
        __builtin_amdgcn_s_barrier();

        // ---- phase 3: quadrant (1,0) ----
        LOAD_B(0, smB);
        STAGE_A(1, nb, kn);
        asm volatile("s_waitcnt vmcnt(4)" ::: "memory");   // retires A0',B0' for next ph0
        __builtin_amdgcn_s_barrier();
        asm volatile("s_waitcnt lgkmcnt(0)" ::: "memory");
        __builtin_amdgcn_sched_barrier(0);
        __builtin_amdgcn_s_setprio(1);
        MFMA_Q(1, 0);
        __builtin_amdgcn_s_setprio(0);
        __builtin_amdgcn_s_barrier();
    }
    // drain dead tail prefetches before LDS dealloc at endpgm
    asm volatile("s_waitcnt vmcnt(0)" ::: "memory");

    // ---- epilogue: C/D layout col = lane&15, row = (lane>>4)*4 + reg ----
    if (FUSE) {
        const int orow = m0 + wm * 128;
        const int ocol = n0 + wn * 32;
#pragma unroll
        for (int i = 0; i < 8; i++)
#pragma unroll
            for (int j2 = 0; j2 < 2; j2++)
#pragma unroll
                for (int r = 0; r < 4; r++) {
                    const float g = acc[i][j2][r];
                    const float u = acc[i][j2 + 2][r];
                    const float a = (g / (1.f + __expf(-g))) * u;
                    actout[(size_t)(orow + i * 16 + kg * 4 + r) * INTER + ocol + j2 * 16 + lm] =
                        __float2bfloat16(a);
                }
    } else {
        const int orow = m0 + wm * 128;
        const int ocol = n0 + wn * 64;
#pragma unroll
        for (int i = 0; i < 8; i++)
#pragma unroll
            for (int j = 0; j < 4; j++)
#pragma unroll
                for (int r = 0; r < 4; r++)
                    cout[(size_t)(orow + i * 16 + kg * 4 + r) * HIDDEN + ocol + j * 16 + lm] =
                        acc[i][j][r];
    }
#undef STAGE_A
#undef STAGE_B
#undef LOAD_A
#undef LOAD_B
#undef MFMA_Q
}

// ---------------------------------------------------------------------------
extern "C" void kernel_launch(void* const* d_in, const int* in_sizes, int n_in,
                              void* d_out, int out_size, void* d_ws, size_t ws_size,
                              hipStream_t stream) {
    const float* h   = (const float*)d_in[0];   // [2,4096,2048]
    const float* wgu = (const float*)d_in[1];   // [16384,2048]
    const float* wd  = (const float*)d_in[2];   // [2048,8192]
    float* out = (float*)d_out;                 // [2,4096,2048]

    char* ws = (char*)d_ws;
    bf16* hbf   = (bf16*)(ws);                   //  33,554,432 B
    bf16* wgubf = (bf16*)(ws + 33554432ull);     //  67,108,864 B
    bf16* wdbf  = (bf16*)(ws + 100663296ull);    //  33,554,432 B
    bf16* actbf = (bf16*)(ws + 134217728ull);    // 134,217,728 B

    cvt_bf16<<<dim3(4096), 256, 0, stream>>>(h,   hbf,   M_TOK * HIDDEN);
    cvt_bf16<<<dim3(8192), 256, 0, stream>>>(wgu, wgubf, 2 * INTER * HIDDEN);
    cvt_bf16<<<dim3(4096), 256, 0, stream>>>(wd,  wdbf,  HIDDEN * INTER);

    // GEMM1 + silu: 256 tokens x 128 act cols per block
    //   x = INTER/128 = 64 col blocks, y = M_TOK/256 = 32 row blocks -> 2048 blocks
    gemm_8ph<HIDDEN, true><<<dim3(64, 32), 512, 0, stream>>>(hbf, wgubf, actbf, nullptr);

    // GEMM2: no split-K; grid (HIDDEN/256 = 8, M_TOK/256 = 32) = 256 blocks = 1/CU
    gemm_8ph<INTER, false><<<dim3(8, 32), 512, 0, stream>>>(actbf, wdbf, nullptr, out);
}

// Round 4
// 952.918 us; speedup vs baseline: 1.3538x; 1.0219x over previous
//
#include <hip/hip_runtime.h>
#include <hip/hip_bf16.h>
#include <cstdint>
#include <cstddef>

#define HIDDEN 2048
#define INTER 8192
#define M_TOK 8192   // BATCH * LOCAL_SEQ = 2 * 4096

typedef __attribute__((ext_vector_type(8))) short short8;   // 8 bf16 = 4 VGPRs
typedef __attribute__((ext_vector_type(4))) float float4v;  // MFMA C/D

typedef __hip_bfloat16 bf16;

// ---------------------------------------------------------------------------
// fp32 -> bf16 convert (memory-bound, grid-stride)
// ---------------------------------------------------------------------------
__global__ void cvt_bf16(const float* __restrict__ src, bf16* __restrict__ dst, int n) {
    int idx = blockIdx.x * blockDim.x + threadIdx.x;
    int stride = gridDim.x * blockDim.x;
    for (int i = idx * 4; i < n; i += stride * 4) {
        float4 v = *(const float4*)(src + i);
        union { bf16 h[4]; ushort4 u; } pk;
        pk.h[0] = __float2bfloat16(v.x);
        pk.h[1] = __float2bfloat16(v.y);
        pk.h[2] = __float2bfloat16(v.z);
        pk.h[3] = __float2bfloat16(v.w);
        *(ushort4*)(dst + i) = pk.u;
    }
}

// async global->LDS, 16B per lane; LDS dest = wave-uniform base + lane*16
__device__ __forceinline__ void load16_lds(const bf16* g, bf16* l) {
    __builtin_amdgcn_global_load_lds((const __attribute__((address_space(1))) void*)g,
                                     (__attribute__((address_space(3))) void*)l,
                                     16, 0, 0);
}

// ---------------------------------------------------------------------------
// 256x256-tile, BK=64, 8-wave, double-buffered 128 KiB LDS.
// R3: ONE barrier per phase (before MFMA). R2's two-barrier lockstep measured
// phase-serial (5030 cyc/tile = LDS 2688 + MFMA 2483, MfmaUtil 47%); single
// barrier lets phase p+1's ds_reads overlap phase p's MFMA across waves.
//
// LDS physical row permutation (R1 fix) unchanged:
//   A: phys p = ih*128 + wm*64 + s  <-> global row m0 + wm*128 + ih*64 + s
//   B: phys p = jh*128 + wn*32 + s  <-> out col  n0 + wn*64 + jh*32 + s
//   (FUSE: phys 0..127 gate, 128..255 up). Swizzle: slot c ^ (r&7), applied
//   on the global source; LDS dest linear (global_load_lds requirement).
//
// Phase structure (per K-tile; stages into nb, reads from bb):
//   ph0: stage A0'; read A0->af, B0->bq ; vmcnt(4)[ret B1'] ; bar; MFMA(0,0)
//   ph1: stage B0'; read B1->bq2        ; vmcnt(4)[ret A1'] ; bar; MFMA(0,1)
//   ph2: stage B1'; read A1->af (reuse) ;                  ; bar; MFMA(1,1)
//   ph3: stage A1'; (no reads, bq held) ; vmcnt(4)[ret A0',B0']; bar; MFMA(1,0)
// RAW: every stage vmcnt-retired before a barrier preceding its first read
//   (FIFO sim: prologue->[B1,A1]; ph0 +A0' ret B1; ph1 +B0' ret A1; ph2 +B1';
//    ph3 +A1' ret A0',B0'; in-flight 4..8, never 0).
// WAR: ph3 has no LDS reads; every read drains via its MFMA's dataflow
//   lgkm-wait before the wave's ph3 barrier; first overwrite of a buffer
//   issues after that barrier.
// ---------------------------------------------------------------------------
template<int KDIM, bool FUSE>
__global__ __launch_bounds__(512, 2) void gemm_8ph(const bf16* __restrict__ A,
                                                   const bf16* __restrict__ B,
                                                   bf16* __restrict__ actout,
                                                   float* __restrict__ cout) {
    static_assert(KDIM % 64 == 0, "KDIM multiple of 64");
    __shared__ __align__(16) bf16 sm[2 * 32768];   // 131072 B

    constexpr int NKT = KDIM / 64;

    const int tid  = threadIdx.x;
    const int wave = tid >> 6;
    const int lane = tid & 63;
    const int wm = wave >> 2;          // 0..1 : M-half of C
    const int wn = wave & 3;           // 0..3 : N-quarter of C
    const int lm = lane & 15;
    const int kg = lane >> 4;

    const int m0 = blockIdx.y * 256;
    const int n0 = blockIdx.x * (FUSE ? 128 : 256);

    // ---- staging addresses: issue q writes LDS phys rows q*64 .. q*64+63 ----
    const int srow = wave * 8 + (lane >> 3);           // phys row within issue
    const int scol = ((lane & 7) ^ (lane >> 3)) * 8;   // pre-swizzled global k-chunk
    const bf16* ag[4];
    const bf16* bg[4];
#pragma unroll
    for (int q = 0; q < 4; ++q) {
        const int arow = m0 + (q & 1) * 128 + (q >> 1) * 64 + srow;
        ag[q] = A + (size_t)arow * KDIM + scol;
        int brow;
        if (FUSE) {
            brow = n0 + (q >> 1) * (INTER - 128) + q * 64 + srow;
        } else {
            const int t = (q & 1) * 64 + srow;
            brow = n0 + (t >> 5) * 64 + (q >> 1) * 32 + (t & 31);
        }
        bg[q] = B + (size_t)brow * KDIM + scol;
    }
    bf16* const sdA = sm + wave * 512;
    bf16* const sdB = sm + 16384 + wave * 512;

    // ---- fragment read slot offsets (loop-invariant per lane) ----
    const int sl0 = ((0 * 4 + kg) ^ (lm & 7)) * 8;   // ks = 0
    const int sl1 = ((1 * 4 + kg) ^ (lm & 7)) * 8;   // ks = 1

    float4v acc[8][4];
#pragma unroll
    for (int i = 0; i < 8; i++)
#pragma unroll
        for (int j = 0; j < 4; j++) acc[i][j] = (float4v)0.f;

    short8 af[8];    // current A-half (A0 in ph0/1, A1 in ph2/3)
    short8 bq[4];    // B-grp0, held ph0..ph3
    short8 bq2[4];   // B-grp1, held ph1..ph2

#define STAGE_A(h, nb, kn) { \
        load16_lds(ag[(h)*2+0] + (size_t)(kn)*64, sdA + (nb)*32768 + ((h)*2+0)*4096); \
        load16_lds(ag[(h)*2+1] + (size_t)(kn)*64, sdA + (nb)*32768 + ((h)*2+1)*4096); }
#define STAGE_B(h, nb, kn) { \
        load16_lds(bg[(h)*2+0] + (size_t)(kn)*64, sdB + (nb)*32768 + ((h)*2+0)*4096); \
        load16_lds(bg[(h)*2+1] + (size_t)(kn)*64, sdB + (nb)*32768 + ((h)*2+1)*4096); }
#define LOAD_A(dst, ih, smA_) { \
        _Pragma("unroll") \
        for (int i2 = 0; i2 < 4; i2++) { \
            const bf16* p = (smA_) + ((ih) * 128 + wm * 64 + i2 * 16 + lm) * 64; \
            dst[i2*2+0] = *(const short8*)(p + sl0); \
            dst[i2*2+1] = *(const short8*)(p + sl1); } }
#define LOAD_B(dst, jh, smB_) { \
        _Pragma("unroll") \
        for (int j2 = 0; j2 < 2; j2++) { \
            const bf16* p = (smB_) + ((jh) * 128 + wn * 32 + j2 * 16 + lm) * 64; \
            dst[j2*2+0] = *(const short8*)(p + sl0); \
            dst[j2*2+1] = *(const short8*)(p + sl1); } }
#define MFMA_Q(A_, B_, ih, jh) { \
        _Pragma("unroll") \
        for (int i2 = 0; i2 < 4; i2++) \
        _Pragma("unroll") \
        for (int j2 = 0; j2 < 2; j2++) { \
            acc[(ih)*4+i2][(jh)*2+j2] = __builtin_amdgcn_mfma_f32_16x16x32_bf16(A_[i2*2+0], B_[j2*2+0], acc[(ih)*4+i2][(jh)*2+j2], 0, 0, 0); \
            acc[(ih)*4+i2][(jh)*2+j2] = __builtin_amdgcn_mfma_f32_16x16x32_bf16(A_[i2*2+1], B_[j2*2+1], acc[(ih)*4+i2][(jh)*2+j2], 0, 0, 0); } }
#define FENCE asm volatile("" ::: "memory")
#define BAR   do { FENCE; __builtin_amdgcn_s_barrier(); FENCE; } while (0)

    // ---- prologue: stage tile 0 into buf 0, issue order A0,B0,B1,A1 ----
    STAGE_A(0, 0, 0);
    STAGE_B(0, 0, 0);
    STAGE_B(1, 0, 0);
    STAGE_A(1, 0, 0);
    asm volatile("s_waitcnt vmcnt(4)" ::: "memory");   // A0,B0 landed; B1,A1 in flight
    BAR;

    for (int kt = 0; kt < NKT; ++kt) {
        const int bb = kt & 1;
        const int nb = bb ^ 1;
        const int kn = (kt + 1 < NKT) ? (kt + 1) : 0;   // tail: dead prefetch
        const bf16* smA = sm + bb * 32768;
        const bf16* smB = smA + 16384;

        // ---- phase 0: MFMA(0,0) ----
        STAGE_A(0, nb, kn);
        LOAD_A(af, 0, smA);
        LOAD_B(bq, 0, smB);
        asm volatile("s_waitcnt vmcnt(4)" ::: "memory");   // retires B1'(prev) for ph1
        BAR;
        __builtin_amdgcn_s_setprio(1);
        MFMA_Q(af, bq, 0, 0);
        __builtin_amdgcn_s_setprio(0);
        __builtin_amdgcn_sched_barrier(0);

        // ---- phase 1: MFMA(0,1) ----
        STAGE_B(0, nb, kn);
        LOAD_B(bq2, 1, smB);
        asm volatile("s_waitcnt vmcnt(4)" ::: "memory");   // retires A1'(prev) for ph2
        BAR;
        __builtin_amdgcn_s_setprio(1);
        MFMA_Q(af, bq2, 0, 1);
        __builtin_amdgcn_s_setprio(0);
        __builtin_amdgcn_sched_barrier(0);

        // ---- phase 2: MFMA(1,1) ----
        STAGE_B(1, nb, kn);
        LOAD_A(af, 1, smA);          // overwrite af (A0 dead after ph1)
        BAR;
        __builtin_amdgcn_s_setprio(1);
        MFMA_Q(af, bq2, 1, 1);
        __builtin_amdgcn_s_setprio(0);
        __builtin_amdgcn_sched_barrier(0);

        // ---- phase 3: MFMA(1,0) (no reads; bq held from ph0) ----
        STAGE_A(1, nb, kn);
        asm volatile("s_waitcnt vmcnt(4)" ::: "memory");   // retires A0',B0' for next ph0
        BAR;
        __builtin_amdgcn_s_setprio(1);
        MFMA_Q(af, bq, 1, 0);
        __builtin_amdgcn_s_setprio(0);
        __builtin_amdgcn_sched_barrier(0);
    }
    // drain dead tail prefetches before LDS dealloc at endpgm
    asm volatile("s_waitcnt vmcnt(0)" ::: "memory");

    // ---- epilogue: C/D layout col = lane&15, row = (lane>>4)*4 + reg ----
    if (FUSE) {
        const int orow = m0 + wm * 128;
        const int ocol = n0 + wn * 32;
#pragma unroll
        for (int i = 0; i < 8; i++)
#pragma unroll
            for (int j2 = 0; j2 < 2; j2++)
#pragma unroll
                for (int r = 0; r < 4; r++) {
                    const float g = acc[i][j2][r];
                    const float u = acc[i][j2 + 2][r];
                    const float a = (g / (1.f + __expf(-g))) * u;
                    actout[(size_t)(orow + i * 16 + kg * 4 + r) * INTER + ocol + j2 * 16 + lm] =
                        __float2bfloat16(a);
                }
    } else {
        const int orow = m0 + wm * 128;
        const int ocol = n0 + wn * 64;
#pragma unroll
        for (int i = 0; i < 8; i++)
#pragma unroll
            for (int j = 0; j < 4; j++)
#pragma unroll
                for (int r = 0; r < 4; r++)
                    cout[(size_t)(orow + i * 16 + kg * 4 + r) * HIDDEN + ocol + j * 16 + lm] =
                        acc[i][j][r];
    }
#undef STAGE_A
#undef STAGE_B
#undef LOAD_A
#undef LOAD_B
#undef MFMA_Q
#undef FENCE
#undef BAR
}

// ---------------------------------------------------------------------------
extern "C" void kernel_launch(void* const* d_in, const int* in_sizes, int n_in,
                              void* d_out, int out_size, void* d_ws, size_t ws_size,
                              hipStream_t stream) {
    const float* h   = (const float*)d_in[0];   // [2,4096,2048]
    const float* wgu = (const float*)d_in[1];   // [16384,2048]
    const float* wd  = (const float*)d_in[2];   // [2048,8192]
    float* out = (float*)d_out;                 // [2,4096,2048]

    char* ws = (char*)d_ws;
    bf16* hbf   = (bf16*)(ws);                   //  33,554,432 B
    bf16* wgubf = (bf16*)(ws + 33554432ull);     //  67,108,864 B
    bf16* wdbf  = (bf16*)(ws + 100663296ull);    //  33,554,432 B
    bf16* actbf = (bf16*)(ws + 134217728ull);    // 134,217,728 B

    cvt_bf16<<<dim3(4096), 256, 0, stream>>>(h,   hbf,   M_TOK * HIDDEN);
    cvt_bf16<<<dim3(8192), 256, 0, stream>>>(wgu, wgubf, 2 * INTER * HIDDEN);
    cvt_bf16<<<dim3(4096), 256, 0, stream>>>(wd,  wdbf,  HIDDEN * INTER);

    // GEMM1 + silu: x = INTER/128 = 64 col blocks, y = M_TOK/256 = 32 -> 2048 blocks
    gemm_8ph<HIDDEN, true><<<dim3(64, 32), 512, 0, stream>>>(hbf, wgubf, actbf, nullptr);

    // GEMM2: grid (HIDDEN/256 = 8, M_TOK/256 = 32) = 256 blocks = 1/CU
    gemm_8ph<INTER, false><<<dim3(8, 32), 512, 0, stream>>>(actbf, wdbf, nullptr, out);
}

// Round 5
// 932.409 us; speedup vs baseline: 1.3836x; 1.0220x over previous
//
#include <hip/hip_runtime.h>
#include <hip/hip_bf16.h>
#include <cstdint>
#include <cstddef>

#define HIDDEN 2048
#define INTER 8192
#define M_TOK 8192   // BATCH * LOCAL_SEQ = 2 * 4096

typedef __attribute__((ext_vector_type(8))) short short8;   // 8 bf16 = 4 VGPRs
typedef __attribute__((ext_vector_type(4))) float float4v;  // MFMA C/D

typedef __hip_bfloat16 bf16;

// ---------------------------------------------------------------------------
// fp32 -> bf16 convert (memory-bound, grid-stride)
// ---------------------------------------------------------------------------
__global__ void cvt_bf16(const float* __restrict__ src, bf16* __restrict__ dst, int n) {
    int idx = blockIdx.x * blockDim.x + threadIdx.x;
    int stride = gridDim.x * blockDim.x;
    for (int i = idx * 4; i < n; i += stride * 4) {
        float4 v = *(const float4*)(src + i);
        union { bf16 h[4]; ushort4 u; } pk;
        pk.h[0] = __float2bfloat16(v.x);
        pk.h[1] = __float2bfloat16(v.y);
        pk.h[2] = __float2bfloat16(v.z);
        pk.h[3] = __float2bfloat16(v.w);
        *(ushort4*)(dst + i) = pk.u;
    }
}

// async global->LDS, 16B per lane; LDS dest = wave-uniform base + lane*16
__device__ __forceinline__ void load16_lds(const bf16* g, bf16* l) {
    __builtin_amdgcn_global_load_lds((const __attribute__((address_space(1))) void*)g,
                                     (__attribute__((address_space(3))) void*)l,
                                     16, 0, 0);
}

// ---------------------------------------------------------------------------
// 256x256-tile, BK=64, 8-wave, double-buffered 128 KiB LDS.
// R5: reads one-phase-ahead, placed POST-MFMA (R4 measured 4144 cyc/tile =
// sum of per-phase max(reads, mfma); reads pre-barrier + same-phase consume
// exposed lgkm latency and the 12-read ph0 burst). Now every phase is
//   { stage(2 loads); vmcnt(4); BAR; setprio; MFMA; setprio; sched_bar; reads }
// and each MFMA's operands were read >= 1 full phase earlier, so the
// auto-inserted lgkm wait is ~free and the LDS pipe (2304 cyc/tile) flows
// underneath the MFMA pipe (2483 cyc/tile) with no barrier-forced drain.
//
// Read schedule (quadrants p0=(0,0) p1=(0,1) p2=(1,1) p3=(1,0); af=A-half,
// bq=B0 held all tile, bq2=B1):
//   ph0-post: B1(kt)  -> bq2   (4 reads)  [consumed p1, p2]
//   ph1-post: A1(kt)  -> af    (8)        [consumed p2, p3]
//   ph2-post: none
//   ph3-post: A0(kt+1)-> af, B0(kt+1)-> bq (12)  [consumed p0, p1 / p0, p3]
// vmcnt FIFO (stages: A0'@ph0, B0'@ph1, B1'@ph2, A1'@ph3; uniform vmcnt(4)):
//   ph0 entry [B1,A1]+A0' =6 -> ret B1(kt) ; ph1 +B0' =6 -> ret A1(kt) ;
//   ph2 +B1' =6 -> ret A0' ; ph3 +A1' =6 -> ret B0'. In-flight 4..6.
// Every read's producer stage is vmcnt-retired (own wait) before a barrier
// that precedes the read -> all-wave safe. WAR: first overwrite of a buffer
// trails its last read by >= 2 barriers.
//
// LDS row permutation + XOR swizzle unchanged (R1/R2, conflicts = 0):
//   A phys p = ih*128+wm*64+s <-> global row m0+wm*128+ih*64+s
//   B phys p = jh*128+wn*32+s <-> out col n0+wn*64+jh*32+s (FUSE: gate|up)
//   slot c ^ (r&7) applied on the global source, LDS dest linear.
//
// XCD swizzle (T1): dispatch id -> XCD = id&7 (round-robin); cluster by so
// same-A-panel blocks share one XCD's L2 (gemm2 was ~half of gemm1's FLOP
// but ~same time -> A panel re-fetched ~8x across XCDs, HBM-bound).
// ---------------------------------------------------------------------------
template<int KDIM, bool FUSE>
__global__ __launch_bounds__(512, 2) void gemm_8ph(const bf16* __restrict__ A,
                                                   const bf16* __restrict__ B,
                                                   bf16* __restrict__ actout,
                                                   float* __restrict__ cout) {
    static_assert(KDIM % 64 == 0, "KDIM multiple of 64");
    __shared__ __align__(16) bf16 sm[2 * 32768];   // 131072 B

    constexpr int NKT = KDIM / 64;

    const int tid  = threadIdx.x;
    const int wave = tid >> 6;
    const int lane = tid & 63;
    const int wm = wave >> 2;          // 0..1 : M-half of C
    const int wn = wave & 3;           // 0..3 : N-quarter of C
    const int lm = lane & 15;
    const int kg = lane >> 4;

    // XCD-aware swizzle: id&7 = XCD; 4 consecutive by per XCD (gy = 32).
    const int id = blockIdx.y * gridDim.x + blockIdx.x;
    const int w_ = id >> 3;
    const int by = (id & 7) * 4 + (w_ & 3);
    const int bx = w_ >> 2;

    const int m0 = by * 256;
    const int n0 = bx * (FUSE ? 128 : 256);

    // ---- staging addresses: issue q writes LDS phys rows q*64 .. q*64+63 ----
    const int srow = wave * 8 + (lane >> 3);           // phys row within issue
    const int scol = ((lane & 7) ^ (lane >> 3)) * 8;   // pre-swizzled global k-chunk
    const bf16* ag[4];
    const bf16* bg[4];
#pragma unroll
    for (int q = 0; q < 4; ++q) {
        const int arow = m0 + (q & 1) * 128 + (q >> 1) * 64 + srow;
        ag[q] = A + (size_t)arow * KDIM + scol;
        int brow;
        if (FUSE) {
            brow = n0 + (q >> 1) * (INTER - 128) + q * 64 + srow;
        } else {
            const int t = (q & 1) * 64 + srow;
            brow = n0 + (t >> 5) * 64 + (q >> 1) * 32 + (t & 31);
        }
        bg[q] = B + (size_t)brow * KDIM + scol;
    }
    bf16* const sdA = sm + wave * 512;
    bf16* const sdB = sm + 16384 + wave * 512;

    // ---- fragment read slot offsets (loop-invariant per lane) ----
    const int sl0 = ((0 * 4 + kg) ^ (lm & 7)) * 8;   // ks = 0
    const int sl1 = ((1 * 4 + kg) ^ (lm & 7)) * 8;   // ks = 1

    float4v acc[8][4];
#pragma unroll
    for (int i = 0; i < 8; i++)
#pragma unroll
        for (int j = 0; j < 4; j++) acc[i][j] = (float4v)0.f;

    short8 af[8];    // A-half: A0 (ph3-post..p1), A1 (ph1-post..p3)
    short8 bq[4];    // B-grp0: held full tile (p0, p3)
    short8 bq2[4];   // B-grp1: ph0-post..p2

#define STAGE_A(h, nb, kn) { \
        load16_lds(ag[(h)*2+0] + (size_t)(kn)*64, sdA + (nb)*32768 + ((h)*2+0)*4096); \
        load16_lds(ag[(h)*2+1] + (size_t)(kn)*64, sdA + (nb)*32768 + ((h)*2+1)*4096); }
#define STAGE_B(h, nb, kn) { \
        load16_lds(bg[(h)*2+0] + (size_t)(kn)*64, sdB + (nb)*32768 + ((h)*2+0)*4096); \
        load16_lds(bg[(h)*2+1] + (size_t)(kn)*64, sdB + (nb)*32768 + ((h)*2+1)*4096); }
#define LOAD_A(dst, ih, smA_) { \
        _Pragma("unroll") \
        for (int i2 = 0; i2 < 4; i2++) { \
            const bf16* p = (smA_) + ((ih) * 128 + wm * 64 + i2 * 16 + lm) * 64; \
            dst[i2*2+0] = *(const short8*)(p + sl0); \
            dst[i2*2+1] = *(const short8*)(p + sl1); } }
#define LOAD_B(dst, jh, smB_) { \
        _Pragma("unroll") \
        for (int j2 = 0; j2 < 2; j2++) { \
            const bf16* p = (smB_) + ((jh) * 128 + wn * 32 + j2 * 16 + lm) * 64; \
            dst[j2*2+0] = *(const short8*)(p + sl0); \
            dst[j2*2+1] = *(const short8*)(p + sl1); } }
#define MFMA_Q(A_, B_, ih, jh) { \
        _Pragma("unroll") \
        for (int i2 = 0; i2 < 4; i2++) \
        _Pragma("unroll") \
        for (int j2 = 0; j2 < 2; j2++) { \
            acc[(ih)*4+i2][(jh)*2+j2] = __builtin_amdgcn_mfma_f32_16x16x32_bf16(A_[i2*2+0], B_[j2*2+0], acc[(ih)*4+i2][(jh)*2+j2], 0, 0, 0); \
            acc[(ih)*4+i2][(jh)*2+j2] = __builtin_amdgcn_mfma_f32_16x16x32_bf16(A_[i2*2+1], B_[j2*2+1], acc[(ih)*4+i2][(jh)*2+j2], 0, 0, 0); } }
#define FENCE asm volatile("" ::: "memory")
#define BAR   do { FENCE; __builtin_amdgcn_s_barrier(); FENCE; } while (0)
#define VMC4  asm volatile("s_waitcnt vmcnt(4)" ::: "memory")
#define SBAR0 __builtin_amdgcn_sched_barrier(0)

    // ---- prologue: stage tile 0 into buf 0 (A0,B0,B1,A1); preload af,bq ----
    STAGE_A(0, 0, 0);
    STAGE_B(0, 0, 0);
    STAGE_B(1, 0, 0);
    STAGE_A(1, 0, 0);
    VMC4;                       // A0(0), B0(0) landed; B1(0), A1(0) in flight
    BAR;
    LOAD_A(af, 0, sm);          // A0(0)
    LOAD_B(bq, 0, sm + 16384);  // B0(0)

    for (int kt = 0; kt < NKT; ++kt) {
        const int bb = kt & 1;
        const int nb = bb ^ 1;
        const int kn = (kt + 1 < NKT) ? (kt + 1) : 0;   // tail: dead prefetch
        const bf16* smA  = sm + bb * 32768;
        const bf16* smB  = smA + 16384;
        const bf16* smA2 = sm + nb * 32768;
        const bf16* smB2 = smA2 + 16384;

        // ---- phase 0: MFMA p0 (A0 x B0); post-read B1(kt) ----
        STAGE_A(0, nb, kn);
        VMC4;                                   // retires B1(kt)
        BAR;
        __builtin_amdgcn_s_setprio(1);
        MFMA_Q(af, bq, 0, 0);
        __builtin_amdgcn_s_setprio(0);
        SBAR0;
        LOAD_B(bq2, 1, smB);

        // ---- phase 1: MFMA p1 (A0 x B1); post-read A1(kt) ----
        STAGE_B(0, nb, kn);
        VMC4;                                   // retires A1(kt)
        BAR;
        __builtin_amdgcn_s_setprio(1);
        MFMA_Q(af, bq2, 0, 1);
        __builtin_amdgcn_s_setprio(0);
        SBAR0;
        LOAD_A(af, 1, smA);

        // ---- phase 2: MFMA p2 (A1 x B1); no reads ----
        STAGE_B(1, nb, kn);
        VMC4;                                   // retires A0'(next) early
        BAR;
        __builtin_amdgcn_s_setprio(1);
        MFMA_Q(af, bq2, 1, 1);
        __builtin_amdgcn_s_setprio(0);
        SBAR0;

        // ---- phase 3: MFMA p3 (A1 x B0); post-read A0,B0 of next tile ----
        STAGE_A(1, nb, kn);
        VMC4;                                   // retires B0'(next)
        BAR;
        __builtin_amdgcn_s_setprio(1);
        MFMA_Q(af, bq, 1, 0);
        __builtin_amdgcn_s_setprio(0);
        SBAR0;
        LOAD_A(af, 0, smA2);
        LOAD_B(bq, 0, smB2);
    }
    // drain dead tail prefetches before LDS dealloc at endpgm
    asm volatile("s_waitcnt vmcnt(0)" ::: "memory");

    // ---- epilogue: C/D layout col = lane&15, row = (lane>>4)*4 + reg ----
    if (FUSE) {
        const int orow = m0 + wm * 128;
        const int ocol = n0 + wn * 32;
#pragma unroll
        for (int i = 0; i < 8; i++)
#pragma unroll
            for (int j2 = 0; j2 < 2; j2++)
#pragma unroll
                for (int r = 0; r < 4; r++) {
                    const float g = acc[i][j2][r];
                    const float u = acc[i][j2 + 2][r];
                    const float a = (g / (1.f + __expf(-g))) * u;
                    actout[(size_t)(orow + i * 16 + kg * 4 + r) * INTER + ocol + j2 * 16 + lm] =
                        __float2bfloat16(a);
                }
    } else {
        const int orow = m0 + wm * 128;
        const int ocol = n0 + wn * 64;
#pragma unroll
        for (int i = 0; i < 8; i++)
#pragma unroll
            for (int j = 0; j < 4; j++)
#pragma unroll
                for (int r = 0; r < 4; r++)
                    cout[(size_t)(orow + i * 16 + kg * 4 + r) * HIDDEN + ocol + j * 16 + lm] =
                        acc[i][j][r];
    }
#undef STAGE_A
#undef STAGE_B
#undef LOAD_A
#undef LOAD_B
#undef MFMA_Q
#undef FENCE
#undef BAR
#undef VMC4
#undef SBAR0
}

// ---------------------------------------------------------------------------
extern "C" void kernel_launch(void* const* d_in, const int* in_sizes, int n_in,
                              void* d_out, int out_size, void* d_ws, size_t ws_size,
                              hipStream_t stream) {
    const float* h   = (const float*)d_in[0];   // [2,4096,2048]
    const float* wgu = (const float*)d_in[1];   // [16384,2048]
    const float* wd  = (const float*)d_in[2];   // [2048,8192]
    float* out = (float*)d_out;                 // [2,4096,2048]

    char* ws = (char*)d_ws;
    bf16* hbf   = (bf16*)(ws);                   //  33,554,432 B
    bf16* wgubf = (bf16*)(ws + 33554432ull);     //  67,108,864 B
    bf16* wdbf  = (bf16*)(ws + 100663296ull);    //  33,554,432 B
    bf16* actbf = (bf16*)(ws + 134217728ull);    // 134,217,728 B

    cvt_bf16<<<dim3(4096), 256, 0, stream>>>(h,   hbf,   M_TOK * HIDDEN);
    cvt_bf16<<<dim3(8192), 256, 0, stream>>>(wgu, wgubf, 2 * INTER * HIDDEN);
    cvt_bf16<<<dim3(4096), 256, 0, stream>>>(wd,  wdbf,  HIDDEN * INTER);

    // GEMM1 + silu: x = INTER/128 = 64 col blocks, y = M_TOK/256 = 32 -> 2048 blocks
    gemm_8ph<HIDDEN, true><<<dim3(64, 32), 512, 0, stream>>>(hbf, wgubf, actbf, nullptr);

    // GEMM2: grid (HIDDEN/256 = 8, M_TOK/256 = 32) = 256 blocks = 1/CU
    gemm_8ph<INTER, false><<<dim3(8, 32), 512, 0, stream>>>(actbf, wdbf, nullptr, out);
}